// Round 6
// baseline (397.530 us; speedup 1.0000x reference)
//
#include <hip/hip_runtime.h>

#define S_LEN 77
#define NHEAD 12
#define DHEAD 64
#define EMB   768
#define BATCH 512
#define MROWS (BATCH * S_LEN)   /* 39424 */
#define NQKV  (3 * EMB)         /* 2304  */
#define KDIM  768
#define NKT   (KDIM / 64)       /* 12 K-tiles of 64 */

typedef __attribute__((ext_vector_type(8))) short bf16x8;
typedef __attribute__((ext_vector_type(4))) float f32x4;

#define WAITV(n) asm volatile("s_waitcnt vmcnt(" #n ")" ::: "memory")
#define WAITL(n) asm volatile("s_waitcnt lgkmcnt(" #n ")" ::: "memory")
#define SB()     __builtin_amdgcn_sched_barrier(0)

__device__ __forceinline__ unsigned short f2bf(float f) {
  union { float f; unsigned int u; } v; v.f = f;
  unsigned int r = (v.u + 0x7fffu + ((v.u >> 16) & 1u)) >> 16;
  return (unsigned short)r;
}

__device__ __forceinline__ void gload_lds16(const void* g, void* l) {
  __builtin_amdgcn_global_load_lds((__attribute__((address_space(1))) void*)g,
                                   (__attribute__((address_space(3))) void*)l,
                                   16, 0, 0);
}

// ---------------- x fp32 -> bf16 ----------------
__global__ void cvt_f32_bf16(const float4* __restrict__ in,
                             ushort4* __restrict__ out, int n4) {
  int stride = gridDim.x * blockDim.x;
  for (int i = blockIdx.x * blockDim.x + threadIdx.x; i < n4; i += stride) {
    float4 v = in[i];
    ushort4 o;
    o.x = f2bf(v.x); o.y = f2bf(v.y); o.z = f2bf(v.z); o.w = f2bf(v.w);
    out[i] = o;
  }
}

// ---------------- weights: transpose to [N][K] bf16, fuse qkv bias ----------------
__global__ void prep_weights(const float* __restrict__ wq, const float* __restrict__ wk,
                             const float* __restrict__ wv, const float* __restrict__ wo,
                             const float* __restrict__ bq, const float* __restrict__ bk,
                             const float* __restrict__ bv,
                             unsigned short* __restrict__ wqkvT,
                             unsigned short* __restrict__ woT,
                             float* __restrict__ bqkv) {
  int i0 = blockIdx.x * blockDim.x + threadIdx.x;
  int stride = gridDim.x * blockDim.x;
  for (int idx = i0; idx < EMB * NQKV; idx += stride) {
    int k = idx / NQKV, n = idx - k * NQKV;
    const float* w; int c;
    if (n < EMB)          { w = wq; c = n; }
    else if (n < 2 * EMB) { w = wk; c = n - EMB; }
    else                  { w = wv; c = n - 2 * EMB; }
    wqkvT[(size_t)n * EMB + k] = f2bf(w[k * EMB + c]);
  }
  for (int idx = i0; idx < EMB * EMB; idx += stride) {
    int k = idx / EMB, n = idx - k * EMB;
    woT[(size_t)n * EMB + k] = f2bf(wo[idx]);
  }
  for (int idx = i0; idx < NQKV; idx += stride) {
    bqkv[idx] = (idx < EMB) ? bq[idx]
              : (idx < 2 * EMB ? bk[idx - EMB] : bv[idx - 2 * EMB]);
  }
}

// ---------------- 256x256 GEMM with A-frag register pipeline ----------------
// BK=64, 8 waves (2Mx4N), 2-slot LDS dbuf (128 KiB). Phase p reads quad p+1
// into the idle A-reg buffer while MFMA(quad p) runs; counted lgkmcnt(4) keeps
// the prefetched reads in flight (LDS pipe || matrix pipe). T1 XCD swizzle,
// T2 read swizzle, T4 counted vmcnt, T5 setprio. Sync skeleton = round-5
// (2 barriers/phase), ledger re-verified.
// MODE 0: C = bf16( (A*B + bias) * (col<768 ? 0.125 : 1) ), stride NQKV
// MODE 1: C = f32 ( A*B + bias ), stride EMB
template <int MODE>
__global__ __launch_bounds__(512, 2) void gemm256(const unsigned short* __restrict__ A,
                                                  const unsigned short* __restrict__ BT,
                                                  const float* __restrict__ bias,
                                                  void* __restrict__ Cout) {
  // slot s (s=0,1) at s*32768 shorts: A tile 256x64 at +0, B tile at +16384
  __shared__ unsigned short lds[2 * 32768];   // 128 KiB

  const int tid  = threadIdx.x;
  const int wave = tid >> 6;
  const int lane = tid & 63;
  const int wr = wave >> 2;        // 0..1  -> rows wr*128..+128
  const int wc = wave & 3;         // 0..3  -> cols wc*64..+64
  const int fr = lane & 15;
  const int fg = lane >> 4;        // 0..3

  // T1: bijective XCD swizzle (m204)
  const int ncol = gridDim.x;
  const int nwg  = gridDim.x * gridDim.y;
  const int orig = blockIdx.y * gridDim.x + blockIdx.x;
  const int q8   = nwg >> 3, r8 = nwg & 7;
  const int xcd  = orig & 7, off = orig >> 3;
  const int swz  = (xcd < r8 ? xcd * (q8 + 1) : r8 * (q8 + 1) + (xcd - r8) * q8) + off;
  const int brow = (swz / ncol) * 256;
  const int bcol = (swz % ncol) * 256;

  f32x4 acc[8][4] = {};

  // Staging round j (j=0..3) covers rows {h*128 + j*32 + 0..31, h=0,1}.
  // thread (w,l): row-in-round = (w>>2)*128 + (w&3)*8 + (l>>3); phys chunk l&7;
  // logical chunk = (l&7) ^ ((l>>3)&7) (inverse of read swizzle, rule 21).
  const int grow = (wave >> 2) * 128 + (wave & 3) * 8 + (lane >> 3);
  const int srcc = (lane & 7) ^ ((lane >> 3) & 7);
  const unsigned short* gA = A  + (size_t)(brow + grow) * KDIM + srcc * 8;
  const unsigned short* gB = BT + (size_t)(bcol + grow) * KDIM + srcc * 8;
  const int wbase = (wave >> 2) * 8192 + (wave & 3) * 512;

  auto ALOAD = [&](int t, int j) {
    gload_lds16(gA + (size_t)(j * 32) * KDIM + t * 64,
                lds + (t & 1) * 32768 + wbase + j * 2048);
  };
  auto BLOAD = [&](int t, int j) {
    gload_lds16(gB + (size_t)(j * 32) * KDIM + t * 64,
                lds + (t & 1) * 32768 + 16384 + wbase + j * 2048);
  };

  const int rsw = fr & 7;          // read-side XOR on the 16B chunk index

  // prologue: stage tile 0 (B01,B23,A01,A23); drain all but A23 (steady entry)
  BLOAD(0, 0); BLOAD(0, 1); BLOAD(0, 2); BLOAD(0, 3);
  ALOAD(0, 0); ALOAD(0, 1); ALOAD(0, 2); ALOAD(0, 3);
  WAITV(2);
  SB();
  __builtin_amdgcn_s_barrier();

  for (int t = 0; t < NKT; ++t) {
    const bool st = (t + 1 < NKT);
    const unsigned short* sb  = lds + (t & 1) * 32768;
    const unsigned short* sbB = sb + 16384;
    bf16x8 bfr[4][2], aA[2][2], aB[2][2];

    // helper-free explicit reads (static indices only)
#define READ_A(dst, q)                                                          \
    _Pragma("unroll")                                                           \
    for (int mi = 0; mi < 2; ++mi)                                              \
      _Pragma("unroll")                                                         \
      for (int kk = 0; kk < 2; ++kk)                                            \
        dst[mi][kk] = *(const bf16x8*)(sb + (wr * 128 + ((q) * 2 + mi) * 16 + fr) * 64 + \
                                       (((kk * 4 + fg) ^ rsw) * 8));
#define DO_MFMA(src, q)                                                         \
    __builtin_amdgcn_s_setprio(1);                                              \
    _Pragma("unroll")                                                           \
    for (int kk = 0; kk < 2; ++kk)                                              \
      _Pragma("unroll")                                                         \
      for (int mi = 0; mi < 2; ++mi)                                            \
        _Pragma("unroll")                                                       \
        for (int n = 0; n < 4; ++n)                                             \
          acc[(q) * 2 + mi][n] = __builtin_amdgcn_mfma_f32_16x16x32_bf16(       \
              src[mi][kk], bfr[n][kk], acc[(q) * 2 + mi][n], 0, 0, 0);          \
    __builtin_amdgcn_s_setprio(0);

    // ---- phase 0: read B + q0 + q1; stage B01(t+1); MFMA q0 ----
#pragma unroll
    for (int n = 0; n < 4; ++n)
#pragma unroll
      for (int kk = 0; kk < 2; ++kk)
        bfr[n][kk] = *(const bf16x8*)(sbB + (wc * 64 + n * 16 + fr) * 64 +
                                      (((kk * 4 + fg) ^ rsw) * 8));
    READ_A(aA, 0)
    READ_A(aB, 1)
    if (st) { BLOAD(t + 1, 0); BLOAD(t + 1, 1); }
    SB();
    __builtin_amdgcn_s_barrier();
    WAITL(4); SB();                 // drain B+q0, keep q1 in flight
    DO_MFMA(aA, 0)
    SB();
    if (st) { WAITV(2); } else { WAITV(0); }   // drain A23(t) globally via barrier
    __builtin_amdgcn_s_barrier();

    // ---- phase 1: read q2 (over MFMA q1); stage B23(t+1) ----
    READ_A(aA, 2)
    if (st) { BLOAD(t + 1, 2); BLOAD(t + 1, 3); }
    SB();
    __builtin_amdgcn_s_barrier();
    WAITL(4); SB();                 // drain q1, keep q2
    DO_MFMA(aB, 1)
    SB();
    __builtin_amdgcn_s_barrier();

    // ---- phase 2: read q3 (over MFMA q2); stage A01(t+1) ----
    READ_A(aB, 3)
    if (st) { ALOAD(t + 1, 0); ALOAD(t + 1, 1); }
    SB();
    __builtin_amdgcn_s_barrier();
    WAITL(4); SB();                 // drain q2, keep q3
    DO_MFMA(aA, 2)
    SB();
    __builtin_amdgcn_s_barrier();

    // ---- phase 3: stage A23(t+1); MFMA q3 ----
    if (st) { ALOAD(t + 1, 2); ALOAD(t + 1, 3); }
    SB();
    __builtin_amdgcn_s_barrier();
    WAITL(0); SB();
    DO_MFMA(aB, 3)
    SB();
    if (st) { WAITV(2); }           // drain B01,B23,A01(t+1); keep A23(t+1)
    __builtin_amdgcn_s_barrier();
#undef READ_A
#undef DO_MFMA
  }

  // epilogue: n innermost so both 32B halves of each 64B line store back-to-back
  float bvals[4];
#pragma unroll
  for (int n = 0; n < 4; ++n) bvals[n] = bias[bcol + wc * 64 + n * 16 + fr];
#pragma unroll
  for (int m = 0; m < 8; ++m) {
#pragma unroll
    for (int r = 0; r < 4; ++r) {
      const int row = brow + wr * 128 + m * 16 + fg * 4 + r;
#pragma unroll
      for (int n = 0; n < 4; ++n) {
        const int col = bcol + wc * 64 + n * 16 + fr;
        float v = acc[m][n][r] + bvals[n];
        if (MODE == 0) {
          if (col < EMB) v *= 0.125f;
          ((unsigned short*)Cout)[(size_t)row * NQKV + col] = f2bf(v);
        } else {
          ((float*)Cout)[(size_t)row * EMB + col] = v;
        }
      }
    }
  }
}

// ---------------- attention: one block per (b,h), 5 waves (16-row stripes) ----------------
__global__ __launch_bounds__(320) void attn_kernel(const unsigned short* __restrict__ qkv,
                                                   unsigned short* __restrict__ attn_out) {
  __shared__ unsigned short q_lds[80 * 72];    // rows 0..79, stride 72 bf16 (144B)
  __shared__ unsigned short k_lds[80 * 72];
  __shared__ unsigned short vT_lds[64 * 104];  // [d][t], stride 104 bf16 (208B)
  __shared__ unsigned short p_lds[80 * 104];   // [s][t]

  const int tid  = threadIdx.x;
  const int wv_  = tid >> 6;   // stripe 0..4
  const int lane = tid & 63;
  const int fr = lane & 15;
  const int fg = lane >> 4;

  const int bh = blockIdx.x;
  const int b  = bh / NHEAD;
  const int h  = bh - b * NHEAD;

  // zero-fill (covers all pad rows/cols)
  for (int i = tid; i < 2880; i += 320) { ((unsigned int*)q_lds)[i] = 0u; ((unsigned int*)k_lds)[i] = 0u; }
  for (int i = tid; i < 3328; i += 320) ((unsigned int*)vT_lds)[i] = 0u;
  for (int i = tid; i < 4160; i += 320) ((unsigned int*)p_lds)[i] = 0u;
  __syncthreads();

  // stage q,k rows and transpose v: c covers ALL 32 uint pairs (d = 0..63)
  const size_t base = (size_t)b * S_LEN * NQKV + (size_t)h * DHEAD;
  for (int idx = tid; idx < S_LEN * 32; idx += 320) {
    int s = idx >> 5, c = idx & 31;
    const unsigned short* src = qkv + base + (size_t)s * NQKV + c * 2;
    unsigned int vq = *(const unsigned int*)(src);
    unsigned int vk = *(const unsigned int*)(src + EMB);
    unsigned int vx = *(const unsigned int*)(src + 2 * EMB);
    *(unsigned int*)(q_lds + s * 72 + c * 2) = vq;
    *(unsigned int*)(k_lds + s * 72 + c * 2) = vk;
    vT_lds[(c * 2 + 0) * 104 + s] = (unsigned short)(vx & 0xffffu);
    vT_lds[(c * 2 + 1) * 104 + s] = (unsigned short)(vx >> 16);
  }
  __syncthreads();

  // QK^T : scores[s][t], s in stripe, t in 0..79, K=64
  f32x4 sc[5];
#pragma unroll
  for (int n = 0; n < 5; ++n) sc[n] = (f32x4){0.f, 0.f, 0.f, 0.f};
#pragma unroll
  for (int kk = 0; kk < 64; kk += 32) {
    bf16x8 afr = *(const bf16x8*)(q_lds + (wv_ * 16 + fr) * 72 + kk + fg * 8);
#pragma unroll
    for (int n = 0; n < 5; ++n) {
      bf16x8 bfr = *(const bf16x8*)(k_lds + (n * 16 + fr) * 72 + kk + fg * 8);
      sc[n] = __builtin_amdgcn_mfma_f32_16x16x32_bf16(afr, bfr, sc[n], 0, 0, 0);
    }
  }

  // causal softmax; rows per lane: s = wv_*16 + fg*4 + r, cols t = n*16 + fr
  float mrow[4], ssum[4];
#pragma unroll
  for (int r = 0; r < 4; ++r) {
    const int s_loc = wv_ * 16 + fg * 4 + r;
    float mx = -1e30f;
#pragma unroll
    for (int n = 0; n < 5; ++n) {
      const int t = n * 16 + fr;
      float val = ((t <= s_loc) && (t < S_LEN)) ? sc[n][r] : -1e30f;
      sc[n][r] = val;
      mx = fmaxf(mx, val);
    }
    mrow[r] = mx;
  }
#pragma unroll
  for (int off = 1; off < 16; off <<= 1)
#pragma unroll
    for (int r = 0; r < 4; ++r)
      mrow[r] = fmaxf(mrow[r], __shfl_xor(mrow[r], off, 64));
#pragma unroll
  for (int r = 0; r < 4; ++r) {
    float sm = 0.f;
#pragma unroll
    for (int n = 0; n < 5; ++n) {
      float p = __expf(sc[n][r] - mrow[r]);
      sc[n][r] = p;
      sm += p;
    }
    ssum[r] = sm;
  }
#pragma unroll
  for (int off = 1; off < 16; off <<= 1)
#pragma unroll
    for (int r = 0; r < 4; ++r)
      ssum[r] += __shfl_xor(ssum[r], off, 64);

#pragma unroll
  for (int r = 0; r < 4; ++r) {
    const int srow = wv_ * 16 + fg * 4 + r;
    const float inv = 1.0f / ssum[r];
#pragma unroll
    for (int n = 0; n < 5; ++n)
      p_lds[srow * 104 + n * 16 + fr] = f2bf(sc[n][r] * inv);
  }
  __syncthreads();

  // PV : out[s][d] = sum_t p[s][t] * v[t][d], K padded to 96 (zeros)
  f32x4 o[4];
#pragma unroll
  for (int n = 0; n < 4; ++n) o[n] = (f32x4){0.f, 0.f, 0.f, 0.f};
#pragma unroll
  for (int kk = 0; kk < 96; kk += 32) {
    bf16x8 afr = *(const bf16x8*)(p_lds + (wv_ * 16 + fr) * 104 + kk + fg * 8);
#pragma unroll
    for (int n = 0; n < 4; ++n) {
      bf16x8 bfr = *(const bf16x8*)(vT_lds + (n * 16 + fr) * 104 + kk + fg * 8);
      o[n] = __builtin_amdgcn_mfma_f32_16x16x32_bf16(afr, bfr, o[n], 0, 0, 0);
    }
  }

  const size_t obase = (size_t)b * S_LEN * EMB + (size_t)h * DHEAD;
#pragma unroll
  for (int r = 0; r < 4; ++r) {
    const int srow = wv_ * 16 + fg * 4 + r;
    if (srow < S_LEN) {
#pragma unroll
      for (int n = 0; n < 4; ++n)
        attn_out[obase + (size_t)srow * EMB + n * 16 + fr] = f2bf(o[n][r]);
    }
  }
}

extern "C" void kernel_launch(void* const* d_in, const int* in_sizes, int n_in,
                              void* d_out, int out_size, void* d_ws, size_t ws_size,
                              hipStream_t stream) {
  const float* x  = (const float*)d_in[0];
  const float* wq = (const float*)d_in[1];
  const float* bq = (const float*)d_in[2];
  const float* wk = (const float*)d_in[3];
  const float* bk = (const float*)d_in[4];
  const float* wv = (const float*)d_in[5];
  const float* bv = (const float*)d_in[6];
  const float* wo = (const float*)d_in[7];
  const float* bo = (const float*)d_in[8];
  (void)in_sizes; (void)n_in; (void)out_size; (void)ws_size;

  char* ws = (char*)d_ws;
  // layout (bytes):
  unsigned short* x_bf   = (unsigned short*)(ws);                  // M*E bf16      = 60,555,264
  unsigned short* wqkvT  = (unsigned short*)(ws + 60555264ULL);    // 2304*768 bf16 =  3,538,944
  unsigned short* woT    = (unsigned short*)(ws + 64094208ULL);    // 768*768 bf16  =  1,179,648
  float*          bqkv   = (float*)         (ws + 65273856ULL);    // 2304 f32      =      9,216
  unsigned short* qkv    = (unsigned short*)(ws + 65283072ULL);    // M*2304 bf16   = 181,665,792
  unsigned short* attn_o = (unsigned short*)(ws + 246948864ULL);   // M*768 bf16    = 60,555,264

  cvt_f32_bf16<<<2048, 256, 0, stream>>>((const float4*)x, (ushort4*)x_bf, MROWS * EMB / 4);
  prep_weights<<<1024, 256, 0, stream>>>(wq, wk, wv, wo, bq, bk, bv, wqkvT, woT, bqkv);
  gemm256<0><<<dim3(NQKV / 256, MROWS / 256), 512, 0, stream>>>(x_bf, wqkvT, bqkv, qkv);
  attn_kernel<<<BATCH * NHEAD, 320, 0, stream>>>(qkv, attn_o);
  gemm256<1><<<dim3(EMB / 256, MROWS / 256), 512, 0, stream>>>(attn_o, woT, bo, d_out);
}

// Round 7
// 380.822 us; speedup vs baseline: 1.0439x; 1.0439x over previous
//
#include <hip/hip_runtime.h>

#define S_LEN 77
#define NHEAD 12
#define DHEAD 64
#define EMB   768
#define BATCH 512
#define MROWS (BATCH * S_LEN)   /* 39424 */
#define NQKV  (3 * EMB)         /* 2304  */
#define KDIM  768
#define NKT   (KDIM / 64)       /* 12 K-tiles of 64 */

typedef __attribute__((ext_vector_type(8))) short bf16x8;
typedef __attribute__((ext_vector_type(4))) float f32x4;

#define WAITV(n) asm volatile("s_waitcnt vmcnt(" #n ")" ::: "memory")

__device__ __forceinline__ unsigned short f2bf(float f) {
  union { float f; unsigned int u; } v; v.f = f;
  unsigned int r = (v.u + 0x7fffu + ((v.u >> 16) & 1u)) >> 16;
  return (unsigned short)r;
}

__device__ __forceinline__ void gload_lds16(const void* g, void* l) {
  __builtin_amdgcn_global_load_lds((__attribute__((address_space(1))) void*)g,
                                   (__attribute__((address_space(3))) void*)l,
                                   16, 0, 0);
}

// ---------------- x fp32 -> bf16 ----------------
__global__ void cvt_f32_bf16(const float4* __restrict__ in,
                             ushort4* __restrict__ out, int n4) {
  int stride = gridDim.x * blockDim.x;
  for (int i = blockIdx.x * blockDim.x + threadIdx.x; i < n4; i += stride) {
    float4 v = in[i];
    ushort4 o;
    o.x = f2bf(v.x); o.y = f2bf(v.y); o.z = f2bf(v.z); o.w = f2bf(v.w);
    out[i] = o;
  }
}

// ---------------- weights: transpose to [N][K] bf16, fuse qkv bias ----------------
__global__ void prep_weights(const float* __restrict__ wq, const float* __restrict__ wk,
                             const float* __restrict__ wv, const float* __restrict__ wo,
                             const float* __restrict__ bq, const float* __restrict__ bk,
                             const float* __restrict__ bv,
                             unsigned short* __restrict__ wqkvT,
                             unsigned short* __restrict__ woT,
                             float* __restrict__ bqkv) {
  int i0 = blockIdx.x * blockDim.x + threadIdx.x;
  int stride = gridDim.x * blockDim.x;
  for (int idx = i0; idx < EMB * NQKV; idx += stride) {
    int k = idx / NQKV, n = idx - k * NQKV;
    const float* w; int c;
    if (n < EMB)          { w = wq; c = n; }
    else if (n < 2 * EMB) { w = wk; c = n - EMB; }
    else                  { w = wv; c = n - 2 * EMB; }
    wqkvT[(size_t)n * EMB + k] = f2bf(w[k * EMB + c]);
  }
  for (int idx = i0; idx < EMB * EMB; idx += stride) {
    int k = idx / EMB, n = idx - k * EMB;
    woT[(size_t)n * EMB + k] = f2bf(wo[idx]);
  }
  for (int idx = i0; idx < NQKV; idx += stride) {
    bqkv[idx] = (idx < EMB) ? bq[idx]
              : (idx < 2 * EMB ? bk[idx - EMB] : bv[idx - 2 * EMB]);
  }
}

// ---------------- 256x256 8-phase-style GEMM (round-5 version, known-good) ----
// MODE 0: C = bf16( (A*B + bias) * (col<768 ? 0.125 : 1) ), stride NQKV
// MODE 1: C = f32 ( A*B + bias ), stride EMB
template <int MODE>
__global__ __launch_bounds__(512, 2) void gemm256(const unsigned short* __restrict__ A,
                                                  const unsigned short* __restrict__ BT,
                                                  const float* __restrict__ bias,
                                                  void* __restrict__ Cout) {
  // slot s (s=0,1) at s*32768 shorts: A tile 256x64 at +0, B tile at +16384
  __shared__ unsigned short lds[2 * 32768];   // 128 KiB

  const int tid  = threadIdx.x;
  const int wave = tid >> 6;
  const int lane = tid & 63;
  const int wr = wave >> 2;        // 0..1  -> rows wr*128..+128
  const int wc = wave & 3;         // 0..3  -> cols wc*64..+64
  const int fr = lane & 15;
  const int fg = lane >> 4;        // 0..3

  // T1: bijective XCD swizzle (m204)
  const int ncol = gridDim.x;
  const int nwg  = gridDim.x * gridDim.y;
  const int orig = blockIdx.y * gridDim.x + blockIdx.x;
  const int q8   = nwg >> 3, r8 = nwg & 7;
  const int xcd  = orig & 7, off = orig >> 3;
  const int swz  = (xcd < r8 ? xcd * (q8 + 1) : r8 * (q8 + 1) + (xcd - r8) * q8) + off;
  const int brow = (swz / ncol) * 256;
  const int bcol = (swz % ncol) * 256;

  f32x4 acc[8][4] = {};

  const int grow = (wave >> 2) * 128 + (wave & 3) * 8 + (lane >> 3);
  const int srcc = (lane & 7) ^ ((lane >> 3) & 7);
  const unsigned short* gA = A  + (size_t)(brow + grow) * KDIM + srcc * 8;
  const unsigned short* gB = BT + (size_t)(bcol + grow) * KDIM + srcc * 8;
  const int wbase = (wave >> 2) * 8192 + (wave & 3) * 512;

  auto ALOAD = [&](int t, int j) {
    gload_lds16(gA + (size_t)(j * 32) * KDIM + t * 64,
                lds + (t & 1) * 32768 + wbase + j * 2048);
  };
  auto BLOAD = [&](int t, int j) {
    gload_lds16(gB + (size_t)(j * 32) * KDIM + t * 64,
                lds + (t & 1) * 32768 + 16384 + wbase + j * 2048);
  };

  const int rsw = fr & 7;          // read-side XOR on the 16B chunk index

  // prologue: stage tile 0 fully (B rounds then A rounds), wait all but A2,A3
  #pragma unroll
  for (int j = 0; j < 4; ++j) BLOAD(0, j);
  #pragma unroll
  for (int j = 0; j < 4; ++j) ALOAD(0, j);
  WAITV(2);
  __builtin_amdgcn_sched_barrier(0);
  __builtin_amdgcn_s_barrier();

  for (int t = 0; t < NKT; ++t) {
    const bool st = (t + 1 < NKT);             // stage tile t+1 this group
    const unsigned short* sb  = lds + (t & 1) * 32768;
    const unsigned short* sbB = sb + 16384;
    bf16x8 bfr[4][2];
    #pragma unroll
    for (int p = 0; p < 4; ++p) {
      // ---- ds_read: A quadrant (m = 2p, 2p+1), plus all B at p==0 ----
      if (p == 0) {
        #pragma unroll
        for (int n = 0; n < 4; ++n)
          #pragma unroll
          for (int kk = 0; kk < 2; ++kk)
            bfr[n][kk] = *(const bf16x8*)(sbB + (wc * 64 + n * 16 + fr) * 64 +
                                          (((kk * 4 + fg) ^ rsw) * 8));
      }
      bf16x8 afr[2][2];
      #pragma unroll
      for (int mi = 0; mi < 2; ++mi)
        #pragma unroll
        for (int kk = 0; kk < 2; ++kk)
          afr[mi][kk] = *(const bf16x8*)(sb + (wr * 128 + (2 * p + mi) * 16 + fr) * 64 +
                                         (((kk * 4 + fg) ^ rsw) * 8));
      // ---- stage 2 loads for tile t+1: p0:B01 p1:B23 p2:A01 p3:A23 ----
      if (st) {
        if (p < 2) { BLOAD(t + 1, 2 * p);     BLOAD(t + 1, 2 * p + 1); }
        else       { ALOAD(t + 1, 2 * p - 4); ALOAD(t + 1, 2 * p - 3); }
      }
      __builtin_amdgcn_sched_barrier(0);
      __builtin_amdgcn_s_barrier();
      asm volatile("s_waitcnt lgkmcnt(0)" ::: "memory");
      __builtin_amdgcn_sched_barrier(0);
      // ---- 16 MFMA ----
      __builtin_amdgcn_s_setprio(1);
      #pragma unroll
      for (int kk = 0; kk < 2; ++kk)
        #pragma unroll
        for (int mi = 0; mi < 2; ++mi)
          #pragma unroll
          for (int n = 0; n < 4; ++n)
            acc[2 * p + mi][n] = __builtin_amdgcn_mfma_f32_16x16x32_bf16(
                afr[mi][kk], bfr[n][kk], acc[2 * p + mi][n], 0, 0, 0);
      __builtin_amdgcn_s_setprio(0);
      __builtin_amdgcn_sched_barrier(0);
      // ---- counted vmcnt (T4): never drain to 0 while staging ----
      if (p == 1) { if (st) { WAITV(4); } else { WAITV(0); } }
      if (p == 3 && st) { WAITV(2); }
      __builtin_amdgcn_s_barrier();
    }
  }

  // epilogue: n innermost so both 32B halves of each 64B line store back-to-back
  float bvals[4];
#pragma unroll
  for (int n = 0; n < 4; ++n) bvals[n] = bias[bcol + wc * 64 + n * 16 + fr];
#pragma unroll
  for (int m = 0; m < 8; ++m) {
#pragma unroll
    for (int r = 0; r < 4; ++r) {
      const int row = brow + wr * 128 + m * 16 + fg * 4 + r;
#pragma unroll
      for (int n = 0; n < 4; ++n) {
        const int col = bcol + wc * 64 + n * 16 + fr;
        float v = acc[m][n][r] + bvals[n];
        if (MODE == 0) {
          if (col < EMB) v *= 0.125f;
          ((unsigned short*)Cout)[(size_t)row * NQKV + col] = f2bf(v);
        } else {
          ((float*)Cout)[(size_t)row * EMB + col] = v;
        }
      }
    }
  }
}

// ---------------- attention: one block per (b,h), 5 waves (16-row stripes) ----
// Lean version: no q_lds (Q direct to regs), no full zero-fill (only the two
// pad strips that PV actually multiplies by nonzero), one barrier before QK^T.
// LDS 38.3 KB -> 4 blocks/CU.
__global__ __launch_bounds__(320) void attn_kernel(const unsigned short* __restrict__ qkv,
                                                   unsigned short* __restrict__ attn_out) {
  __shared__ unsigned short k_lds[80 * 72];    // [t][d], stride 72
  __shared__ unsigned short vT_lds[64 * 96];   // [d][t], stride 96
  __shared__ unsigned short p_lds[80 * 96];    // [s][t], stride 96

  const int tid  = threadIdx.x;
  const int wv_  = tid >> 6;   // stripe 0..4
  const int lane = tid & 63;
  const int fr = lane & 15;
  const int fg = lane >> 4;

  const int bh = blockIdx.x;
  const int b  = bh / NHEAD;
  const int h  = bh - b * NHEAD;

  const size_t base = (size_t)b * S_LEN * NQKV + (size_t)h * DHEAD;

  // Q fragments: direct global->reg (L2/L3-hot; issued first to hide latency)
  bf16x8 qfr[2];
  {
    const int srow = wv_ * 16 + fr;
    const int qs = (srow < S_LEN) ? srow : 0;   // clamp: pad rows discarded later
    const unsigned short* qg = qkv + base + (size_t)qs * NQKV + fg * 8;
    qfr[0] = *(const bf16x8*)(qg);
    qfr[1] = *(const bf16x8*)(qg + 32);
  }

  // zero ONLY the pad strips PV multiplies by nonzero values:
  //   vT cols 77..95 (64 rows x 19), p cols 80..95 (80 rows x 16)
  for (int i = tid; i < 64 * 19; i += 320) {
    int d = i / 19, c = 77 + (i - d * 19);
    vT_lds[d * 96 + c] = 0;
  }
  for (int i = tid; i < 80 * 16; i += 320) {
    int s = i >> 4, c = 80 + (i & 15);
    p_lds[s * 96 + c] = 0;
  }

  // stage K rows and transposed V (strips above are disjoint from these writes)
  for (int idx = tid; idx < S_LEN * 32; idx += 320) {
    int s = idx >> 5, c = idx & 31;
    const unsigned short* src = qkv + base + (size_t)s * NQKV + c * 2;
    unsigned int vk = *(const unsigned int*)(src + EMB);
    unsigned int vx = *(const unsigned int*)(src + 2 * EMB);
    *(unsigned int*)(k_lds + s * 72 + c * 2) = vk;
    vT_lds[(c * 2 + 0) * 96 + s] = (unsigned short)(vx & 0xffffu);
    vT_lds[(c * 2 + 1) * 96 + s] = (unsigned short)(vx >> 16);
  }
  __syncthreads();

  // QK^T : scores[s][t], s in stripe, t in 0..79, K=64
  f32x4 sc[5];
#pragma unroll
  for (int n = 0; n < 5; ++n) sc[n] = (f32x4){0.f, 0.f, 0.f, 0.f};
#pragma unroll
  for (int kk = 0; kk < 2; ++kk) {
#pragma unroll
    for (int n = 0; n < 5; ++n) {
      bf16x8 bfr = *(const bf16x8*)(k_lds + (n * 16 + fr) * 72 + kk * 32 + fg * 8);
      sc[n] = __builtin_amdgcn_mfma_f32_16x16x32_bf16(qfr[kk], bfr, sc[n], 0, 0, 0);
    }
  }

  // causal softmax; rows per lane: s = wv_*16 + fg*4 + r, cols t = n*16 + fr
  float mrow[4], ssum[4];
#pragma unroll
  for (int r = 0; r < 4; ++r) {
    const int s_loc = wv_ * 16 + fg * 4 + r;
    float mx = -1e30f;
#pragma unroll
    for (int n = 0; n < 5; ++n) {
      const int t = n * 16 + fr;
      float val = ((t <= s_loc) && (t < S_LEN)) ? sc[n][r] : -1e30f;
      sc[n][r] = val;
      mx = fmaxf(mx, val);
    }
    mrow[r] = mx;
  }
#pragma unroll
  for (int off = 1; off < 16; off <<= 1)
#pragma unroll
    for (int r = 0; r < 4; ++r)
      mrow[r] = fmaxf(mrow[r], __shfl_xor(mrow[r], off, 64));
#pragma unroll
  for (int r = 0; r < 4; ++r) {
    float sm = 0.f;
#pragma unroll
    for (int n = 0; n < 5; ++n) {
      float p = __expf(sc[n][r] - mrow[r]);
      sc[n][r] = p;
      sm += p;
    }
    ssum[r] = sm;
  }
#pragma unroll
  for (int off = 1; off < 16; off <<= 1)
#pragma unroll
    for (int r = 0; r < 4; ++r)
      ssum[r] += __shfl_xor(ssum[r], off, 64);

#pragma unroll
  for (int r = 0; r < 4; ++r) {
    const int srow = wv_ * 16 + fg * 4 + r;
    const float inv = 1.0f / ssum[r];
#pragma unroll
    for (int n = 0; n < 5; ++n)
      p_lds[srow * 96 + n * 16 + fr] = f2bf(sc[n][r] * inv);
  }
  __syncthreads();

  // PV : out[s][d] = sum_t p[s][t] * v[t][d], t padded to 96 (pad strips zero)
  f32x4 o[4];
#pragma unroll
  for (int n = 0; n < 4; ++n) o[n] = (f32x4){0.f, 0.f, 0.f, 0.f};
#pragma unroll
  for (int kk = 0; kk < 96; kk += 32) {
    bf16x8 afr = *(const bf16x8*)(p_lds + (wv_ * 16 + fr) * 96 + kk + fg * 8);
#pragma unroll
    for (int n = 0; n < 4; ++n) {
      bf16x8 bfr = *(const bf16x8*)(vT_lds + (n * 16 + fr) * 96 + kk + fg * 8);
      o[n] = __builtin_amdgcn_mfma_f32_16x16x32_bf16(afr, bfr, o[n], 0, 0, 0);
    }
  }

  const size_t obase = (size_t)b * S_LEN * EMB + (size_t)h * DHEAD;
#pragma unroll
  for (int r = 0; r < 4; ++r) {
    const int srow = wv_ * 16 + fg * 4 + r;
    if (srow < S_LEN) {
#pragma unroll
      for (int n = 0; n < 4; ++n)
        attn_out[obase + (size_t)srow * EMB + n * 16 + fr] = f2bf(o[n][r]);
    }
  }
}

extern "C" void kernel_launch(void* const* d_in, const int* in_sizes, int n_in,
                              void* d_out, int out_size, void* d_ws, size_t ws_size,
                              hipStream_t stream) {
  const float* x  = (const float*)d_in[0];
  const float* wq = (const float*)d_in[1];
  const float* bq = (const float*)d_in[2];
  const float* wk = (const float*)d_in[3];
  const float* bk = (const float*)d_in[4];
  const float* wv = (const float*)d_in[5];
  const float* bv = (const float*)d_in[6];
  const float* wo = (const float*)d_in[7];
  const float* bo = (const float*)d_in[8];
  (void)in_sizes; (void)n_in; (void)out_size; (void)ws_size;

  char* ws = (char*)d_ws;
  // layout (bytes):
  unsigned short* x_bf   = (unsigned short*)(ws);                  // M*E bf16      = 60,555,264
  unsigned short* wqkvT  = (unsigned short*)(ws + 60555264ULL);    // 2304*768 bf16 =  3,538,944
  unsigned short* woT    = (unsigned short*)(ws + 64094208ULL);    // 768*768 bf16  =  1,179,648
  float*          bqkv   = (float*)         (ws + 65273856ULL);    // 2304 f32      =      9,216
  unsigned short* qkv    = (unsigned short*)(ws + 65283072ULL);    // M*2304 bf16   = 181,665,792
  unsigned short* attn_o = (unsigned short*)(ws + 246948864ULL);   // M*768 bf16    = 60,555,264

  cvt_f32_bf16<<<2048, 256, 0, stream>>>((const float4*)x, (ushort4*)x_bf, MROWS * EMB / 4);
  prep_weights<<<1024, 256, 0, stream>>>(wq, wk, wv, wo, bq, bk, bv, wqkvT, woT, bqkv);
  gemm256<0><<<dim3(NQKV / 256, MROWS / 256), 512, 0, stream>>>(x_bf, wqkvT, bqkv, qkv);
  attn_kernel<<<BATCH * NHEAD, 320, 0, stream>>>(qkv, attn_o);
  gemm256<1><<<dim3(EMB / 256, MROWS / 256), 512, 0, stream>>>(attn_o, woT, bo, d_out);
}

// Round 8
// 377.607 us; speedup vs baseline: 1.0528x; 1.0085x over previous
//
#include <hip/hip_runtime.h>

#define S_LEN 77
#define NHEAD 12
#define DHEAD 64
#define EMB   768
#define BATCH 512
#define MROWS (BATCH * S_LEN)   /* 39424 */
#define NQKV  (3 * EMB)         /* 2304  */
#define KDIM  768
#define NKT   (KDIM / 64)       /* 12 K-tiles of 64 */

typedef __attribute__((ext_vector_type(8))) short bf16x8;
typedef __attribute__((ext_vector_type(4))) float f32x4;

#define WAITV(n) asm volatile("s_waitcnt vmcnt(" #n ")" ::: "memory")
#define WAITL(n) asm volatile("s_waitcnt lgkmcnt(" #n ")" ::: "memory")

__device__ __forceinline__ unsigned short f2bf(float f) {
  union { float f; unsigned int u; } v; v.f = f;
  unsigned int r = (v.u + 0x7fffu + ((v.u >> 16) & 1u)) >> 16;
  return (unsigned short)r;
}

__device__ __forceinline__ void gload_lds16(const void* g, void* l) {
  __builtin_amdgcn_global_load_lds((__attribute__((address_space(1))) void*)g,
                                   (__attribute__((address_space(3))) void*)l,
                                   16, 0, 0);
}

// ---------------- x fp32 -> bf16 ----------------
__global__ void cvt_f32_bf16(const float4* __restrict__ in,
                             ushort4* __restrict__ out, int n4) {
  int stride = gridDim.x * blockDim.x;
  for (int i = blockIdx.x * blockDim.x + threadIdx.x; i < n4; i += stride) {
    float4 v = in[i];
    ushort4 o;
    o.x = f2bf(v.x); o.y = f2bf(v.y); o.z = f2bf(v.z); o.w = f2bf(v.w);
    out[i] = o;
  }
}

// ---------------- weights: transpose to [N][K] bf16, fuse qkv bias ----------------
__global__ void prep_weights(const float* __restrict__ wq, const float* __restrict__ wk,
                             const float* __restrict__ wv, const float* __restrict__ wo,
                             const float* __restrict__ bq, const float* __restrict__ bk,
                             const float* __restrict__ bv,
                             unsigned short* __restrict__ wqkvT,
                             unsigned short* __restrict__ woT,
                             float* __restrict__ bqkv) {
  int i0 = blockIdx.x * blockDim.x + threadIdx.x;
  int stride = gridDim.x * blockDim.x;
  for (int idx = i0; idx < EMB * NQKV; idx += stride) {
    int k = idx / NQKV, n = idx - k * NQKV;
    const float* w; int c;
    if (n < EMB)          { w = wq; c = n; }
    else if (n < 2 * EMB) { w = wk; c = n - EMB; }
    else                  { w = wv; c = n - 2 * EMB; }
    wqkvT[(size_t)n * EMB + k] = f2bf(w[k * EMB + c]);
  }
  for (int idx = i0; idx < EMB * EMB; idx += stride) {
    int k = idx / EMB, n = idx - k * EMB;
    woT[(size_t)n * EMB + k] = f2bf(wo[idx]);
  }
  for (int idx = i0; idx < NQKV; idx += stride) {
    bqkv[idx] = (idx < EMB) ? bq[idx]
              : (idx < 2 * EMB ? bk[idx - EMB] : bv[idx - 2 * EMB]);
  }
}

// ---------------- 256x256 8-phase-style GEMM (round-5 version, known-good) ----
// MODE 0: C = bf16( (A*B + bias) * (col<768 ? 0.125 : 1) ), stride NQKV
// MODE 1: C = f32 ( A*B + bias ), stride EMB
template <int MODE>
__global__ __launch_bounds__(512, 2) void gemm256(const unsigned short* __restrict__ A,
                                                  const unsigned short* __restrict__ BT,
                                                  const float* __restrict__ bias,
                                                  void* __restrict__ Cout) {
  // slot s (s=0,1) at s*32768 shorts: A tile 256x64 at +0, B tile at +16384
  __shared__ unsigned short lds[2 * 32768];   // 128 KiB

  const int tid  = threadIdx.x;
  const int wave = tid >> 6;
  const int lane = tid & 63;
  const int wr = wave >> 2;        // 0..1  -> rows wr*128..+128
  const int wc = wave & 3;         // 0..3  -> cols wc*64..+64
  const int fr = lane & 15;
  const int fg = lane >> 4;        // 0..3

  // T1: bijective XCD swizzle (m204)
  const int ncol = gridDim.x;
  const int nwg  = gridDim.x * gridDim.y;
  const int orig = blockIdx.y * gridDim.x + blockIdx.x;
  const int q8   = nwg >> 3, r8 = nwg & 7;
  const int xcd  = orig & 7, off = orig >> 3;
  const int swz  = (xcd < r8 ? xcd * (q8 + 1) : r8 * (q8 + 1) + (xcd - r8) * q8) + off;
  const int brow = (swz / ncol) * 256;
  const int bcol = (swz % ncol) * 256;

  f32x4 acc[8][4] = {};

  const int grow = (wave >> 2) * 128 + (wave & 3) * 8 + (lane >> 3);
  const int srcc = (lane & 7) ^ ((lane >> 3) & 7);
  const unsigned short* gA = A  + (size_t)(brow + grow) * KDIM + srcc * 8;
  const unsigned short* gB = BT + (size_t)(bcol + grow) * KDIM + srcc * 8;
  const int wbase = (wave >> 2) * 8192 + (wave & 3) * 512;

  auto ALOAD = [&](int t, int j) {
    gload_lds16(gA + (size_t)(j * 32) * KDIM + t * 64,
                lds + (t & 1) * 32768 + wbase + j * 2048);
  };
  auto BLOAD = [&](int t, int j) {
    gload_lds16(gB + (size_t)(j * 32) * KDIM + t * 64,
                lds + (t & 1) * 32768 + 16384 + wbase + j * 2048);
  };

  const int rsw = fr & 7;          // read-side XOR on the 16B chunk index

  // prologue: stage tile 0 fully (B rounds then A rounds), wait all but A2,A3
  #pragma unroll
  for (int j = 0; j < 4; ++j) BLOAD(0, j);
  #pragma unroll
  for (int j = 0; j < 4; ++j) ALOAD(0, j);
  WAITV(2);
  __builtin_amdgcn_sched_barrier(0);
  __builtin_amdgcn_s_barrier();

  for (int t = 0; t < NKT; ++t) {
    const bool st = (t + 1 < NKT);             // stage tile t+1 this group
    const unsigned short* sb  = lds + (t & 1) * 32768;
    const unsigned short* sbB = sb + 16384;
    bf16x8 bfr[4][2];
    #pragma unroll
    for (int p = 0; p < 4; ++p) {
      // ---- ds_read: A quadrant (m = 2p, 2p+1), plus all B at p==0 ----
      if (p == 0) {
        #pragma unroll
        for (int n = 0; n < 4; ++n)
          #pragma unroll
          for (int kk = 0; kk < 2; ++kk)
            bfr[n][kk] = *(const bf16x8*)(sbB + (wc * 64 + n * 16 + fr) * 64 +
                                          (((kk * 4 + fg) ^ rsw) * 8));
      }
      bf16x8 afr[2][2];
      #pragma unroll
      for (int mi = 0; mi < 2; ++mi)
        #pragma unroll
        for (int kk = 0; kk < 2; ++kk)
          afr[mi][kk] = *(const bf16x8*)(sb + (wr * 128 + (2 * p + mi) * 16 + fr) * 64 +
                                         (((kk * 4 + fg) ^ rsw) * 8));
      // ---- stage 2 loads for tile t+1: p0:B01 p1:B23 p2:A01 p3:A23 ----
      if (st) {
        if (p < 2) { BLOAD(t + 1, 2 * p);     BLOAD(t + 1, 2 * p + 1); }
        else       { ALOAD(t + 1, 2 * p - 4); ALOAD(t + 1, 2 * p - 3); }
      }
      __builtin_amdgcn_sched_barrier(0);
      __builtin_amdgcn_s_barrier();
      asm volatile("s_waitcnt lgkmcnt(0)" ::: "memory");
      __builtin_amdgcn_sched_barrier(0);
      // ---- 16 MFMA ----
      __builtin_amdgcn_s_setprio(1);
      #pragma unroll
      for (int kk = 0; kk < 2; ++kk)
        #pragma unroll
        for (int mi = 0; mi < 2; ++mi)
          #pragma unroll
          for (int n = 0; n < 4; ++n)
            acc[2 * p + mi][n] = __builtin_amdgcn_mfma_f32_16x16x32_bf16(
                afr[mi][kk], bfr[n][kk], acc[2 * p + mi][n], 0, 0, 0);
      __builtin_amdgcn_s_setprio(0);
      __builtin_amdgcn_sched_barrier(0);
      // ---- counted vmcnt (T4): never drain to 0 while staging ----
      if (p == 1) { if (st) { WAITV(4); } else { WAITV(0); } }
      if (p == 3 && st) { WAITV(2); }
      __builtin_amdgcn_s_barrier();
    }
  }

  // epilogue: n innermost so both 32B halves of each 64B line store back-to-back
  float bvals[4];
#pragma unroll
  for (int n = 0; n < 4; ++n) bvals[n] = bias[bcol + wc * 64 + n * 16 + fr];
#pragma unroll
  for (int m = 0; m < 8; ++m) {
#pragma unroll
    for (int r = 0; r < 4; ++r) {
      const int row = brow + wr * 128 + m * 16 + fg * 4 + r;
#pragma unroll
      for (int n = 0; n < 4; ++n) {
        const int col = bcol + wc * 64 + n * 16 + fr;
        float v = acc[m][n][r] + bvals[n];
        if (MODE == 0) {
          if (col < EMB) v *= 0.125f;
          ((unsigned short*)Cout)[(size_t)row * NQKV + col] = f2bf(v);
        } else {
          ((float*)Cout)[(size_t)row * EMB + col] = v;
        }
      }
    }
  }
}

// ---------------- attention: one block per (b,h), 5 waves (16-row stripes) ----
// Bank-conflict-fixed strides: vT/p stride 104 shorts (52 dw, gcd(52,32)=4 ->
// b128 row reads ~2-way (free); V-transpose writes 32-way -> 8-way; p writes
// -> 4-way). Second __syncthreads removed: p_lds is stripe-private (written
// and read by the same wave); DS ops are in-order per wave.
#define SV 104
__global__ __launch_bounds__(320) void attn_kernel(const unsigned short* __restrict__ qkv,
                                                   unsigned short* __restrict__ attn_out) {
  __shared__ unsigned short k_lds[80 * 72];    // [t][d], stride 72
  __shared__ unsigned short vT_lds[64 * SV];   // [d][t], stride 104
  __shared__ unsigned short p_lds[80 * SV];    // [s][t], stride 104

  const int tid  = threadIdx.x;
  const int wv_  = tid >> 6;   // stripe 0..4
  const int lane = tid & 63;
  const int fr = lane & 15;
  const int fg = lane >> 4;

  const int bh = blockIdx.x;
  const int b  = bh / NHEAD;
  const int h  = bh - b * NHEAD;

  const size_t base = (size_t)b * S_LEN * NQKV + (size_t)h * DHEAD;

  // Q fragments: direct global->reg (L2/L3-hot; issued first to hide latency)
  bf16x8 qfr[2];
  {
    const int srow = wv_ * 16 + fr;
    const int qs = (srow < S_LEN) ? srow : 0;   // clamp: pad rows discarded later
    const unsigned short* qg = qkv + base + (size_t)qs * NQKV + fg * 8;
    qfr[0] = *(const bf16x8*)(qg);
    qfr[1] = *(const bf16x8*)(qg + 32);
  }

  // zero ONLY the pad strips PV multiplies by nonzero values:
  //   vT cols 77..95 (64 rows x 19), p cols 80..95 (80 rows x 16)
  for (int i = tid; i < 64 * 19; i += 320) {
    int d = i / 19, c = 77 + (i - d * 19);
    vT_lds[d * SV + c] = 0;
  }
  for (int i = tid; i < 80 * 16; i += 320) {
    int s = i >> 4, c = 80 + (i & 15);
    p_lds[s * SV + c] = 0;
  }

  // stage K rows and transposed V (strips above are disjoint from these writes)
  for (int idx = tid; idx < S_LEN * 32; idx += 320) {
    int s = idx >> 5, c = idx & 31;
    const unsigned short* src = qkv + base + (size_t)s * NQKV + c * 2;
    unsigned int vk = *(const unsigned int*)(src + EMB);
    unsigned int vx = *(const unsigned int*)(src + 2 * EMB);
    *(unsigned int*)(k_lds + s * 72 + c * 2) = vk;
    vT_lds[(c * 2 + 0) * SV + s] = (unsigned short)(vx & 0xffffu);
    vT_lds[(c * 2 + 1) * SV + s] = (unsigned short)(vx >> 16);
  }
  __syncthreads();

  // QK^T : scores[s][t], s in stripe, t in 0..79, K=64
  f32x4 sc[5];
#pragma unroll
  for (int n = 0; n < 5; ++n) sc[n] = (f32x4){0.f, 0.f, 0.f, 0.f};
#pragma unroll
  for (int kk = 0; kk < 2; ++kk) {
#pragma unroll
    for (int n = 0; n < 5; ++n) {
      bf16x8 bfr = *(const bf16x8*)(k_lds + (n * 16 + fr) * 72 + kk * 32 + fg * 8);
      sc[n] = __builtin_amdgcn_mfma_f32_16x16x32_bf16(qfr[kk], bfr, sc[n], 0, 0, 0);
    }
  }

  // causal softmax; rows per lane: s = wv_*16 + fg*4 + r, cols t = n*16 + fr
  float mrow[4], ssum[4];
#pragma unroll
  for (int r = 0; r < 4; ++r) {
    const int s_loc = wv_ * 16 + fg * 4 + r;
    float mx = -1e30f;
#pragma unroll
    for (int n = 0; n < 5; ++n) {
      const int t = n * 16 + fr;
      float val = ((t <= s_loc) && (t < S_LEN)) ? sc[n][r] : -1e30f;
      sc[n][r] = val;
      mx = fmaxf(mx, val);
    }
    mrow[r] = mx;
  }
#pragma unroll
  for (int off = 1; off < 16; off <<= 1)
#pragma unroll
    for (int r = 0; r < 4; ++r)
      mrow[r] = fmaxf(mrow[r], __shfl_xor(mrow[r], off, 64));
#pragma unroll
  for (int r = 0; r < 4; ++r) {
    float sm = 0.f;
#pragma unroll
    for (int n = 0; n < 5; ++n) {
      float p = __expf(sc[n][r] - mrow[r]);
      sc[n][r] = p;
      sm += p;
    }
    ssum[r] = sm;
  }
#pragma unroll
  for (int off = 1; off < 16; off <<= 1)
#pragma unroll
    for (int r = 0; r < 4; ++r)
      ssum[r] += __shfl_xor(ssum[r], off, 64);

#pragma unroll
  for (int r = 0; r < 4; ++r) {
    const int srow = wv_ * 16 + fg * 4 + r;
    const float inv = 1.0f / ssum[r];
#pragma unroll
    for (int n = 0; n < 5; ++n)
      p_lds[srow * SV + n * 16 + fr] = f2bf(sc[n][r] * inv);
  }
  // p_lds is stripe-private (same wave writes then reads); DS ops are in-order
  // per wave -> no block barrier needed. Pin compile order + drain writes.
  __builtin_amdgcn_sched_barrier(0);
  WAITL(0);
  __builtin_amdgcn_sched_barrier(0);

  // PV : out[s][d] = sum_t p[s][t] * v[t][d], t padded to 96 (pad strips zero)
  f32x4 o[4];
#pragma unroll
  for (int n = 0; n < 4; ++n) o[n] = (f32x4){0.f, 0.f, 0.f, 0.f};
#pragma unroll
  for (int kk = 0; kk < 96; kk += 32) {
    bf16x8 afr = *(const bf16x8*)(p_lds + (wv_ * 16 + fr) * SV + kk + fg * 8);
#pragma unroll
    for (int n = 0; n < 4; ++n) {
      bf16x8 bfr = *(const bf16x8*)(vT_lds + (n * 16 + fr) * SV + kk + fg * 8);
      o[n] = __builtin_amdgcn_mfma_f32_16x16x32_bf16(afr, bfr, o[n], 0, 0, 0);
    }
  }

  const size_t obase = (size_t)b * S_LEN * EMB + (size_t)h * DHEAD;
#pragma unroll
  for (int r = 0; r < 4; ++r) {
    const int srow = wv_ * 16 + fg * 4 + r;
    if (srow < S_LEN) {
#pragma unroll
      for (int n = 0; n < 4; ++n)
        attn_out[obase + (size_t)srow * EMB + n * 16 + fr] = f2bf(o[n][r]);
    }
  }
}

extern "C" void kernel_launch(void* const* d_in, const int* in_sizes, int n_in,
                              void* d_out, int out_size, void* d_ws, size_t ws_size,
                              hipStream_t stream) {
  const float* x  = (const float*)d_in[0];
  const float* wq = (const float*)d_in[1];
  const float* bq = (const float*)d_in[2];
  const float* wk = (const float*)d_in[3];
  const float* bk = (const float*)d_in[4];
  const float* wv = (const float*)d_in[5];
  const float* bv = (const float*)d_in[6];
  const float* wo = (const float*)d_in[7];
  const float* bo = (const float*)d_in[8];
  (void)in_sizes; (void)n_in; (void)out_size; (void)ws_size;

  char* ws = (char*)d_ws;
  // layout (bytes):
  unsigned short* x_bf   = (unsigned short*)(ws);                  // M*E bf16      = 60,555,264
  unsigned short* wqkvT  = (unsigned short*)(ws + 60555264ULL);    // 2304*768 bf16 =  3,538,944
  unsigned short* woT    = (unsigned short*)(ws + 64094208ULL);    // 768*768 bf16  =  1,179,648
  float*          bqkv   = (float*)         (ws + 65273856ULL);    // 2304 f32      =      9,216
  unsigned short* qkv    = (unsigned short*)(ws + 65283072ULL);    // M*2304 bf16   = 181,665,792
  unsigned short* attn_o = (unsigned short*)(ws + 246948864ULL);   // M*768 bf16    = 60,555,264

  cvt_f32_bf16<<<2048, 256, 0, stream>>>((const float4*)x, (ushort4*)x_bf, MROWS * EMB / 4);
  prep_weights<<<1024, 256, 0, stream>>>(wq, wk, wv, wo, bq, bk, bv, wqkvT, woT, bqkv);
  gemm256<0><<<dim3(NQKV / 256, MROWS / 256), 512, 0, stream>>>(x_bf, wqkvT, bqkv, qkv);
  attn_kernel<<<BATCH * NHEAD, 320, 0, stream>>>(qkv, attn_o);
  gemm256<1><<<dim3(EMB / 256, MROWS / 256), 512, 0, stream>>>(attn_o, woT, bo, d_out);
}

// Round 9
// 361.625 us; speedup vs baseline: 1.0993x; 1.0442x over previous
//
#include <hip/hip_runtime.h>

#define S_LEN 77
#define NHEAD 12
#define DHEAD 64
#define EMB   768
#define BATCH 512
#define MROWS (BATCH * S_LEN)   /* 39424 */
#define NQKV  (3 * EMB)         /* 2304  */
#define KDIM  768
#define NKT   (KDIM / 64)       /* 12 K-tiles of 64 */

typedef __attribute__((ext_vector_type(8))) short bf16x8;
typedef __attribute__((ext_vector_type(4))) float f32x4;

#define WAITV(n) asm volatile("s_waitcnt vmcnt(" #n ")" ::: "memory")
#define WAITL(n) asm volatile("s_waitcnt lgkmcnt(" #n ")" ::: "memory")

__device__ __forceinline__ unsigned short f2bf(float f) {
  union { float f; unsigned int u; } v; v.f = f;
  unsigned int r = (v.u + 0x7fffu + ((v.u >> 16) & 1u)) >> 16;
  return (unsigned short)r;
}

__device__ __forceinline__ void gload_lds16(const void* g, void* l) {
  __builtin_amdgcn_global_load_lds((__attribute__((address_space(1))) void*)g,
                                   (__attribute__((address_space(3))) void*)l,
                                   16, 0, 0);
}

// ---------------- x fp32 -> bf16 ----------------
__global__ void cvt_f32_bf16(const float4* __restrict__ in,
                             ushort4* __restrict__ out, int n4) {
  int stride = gridDim.x * blockDim.x;
  for (int i = blockIdx.x * blockDim.x + threadIdx.x; i < n4; i += stride) {
    float4 v = in[i];
    ushort4 o;
    o.x = f2bf(v.x); o.y = f2bf(v.y); o.z = f2bf(v.z); o.w = f2bf(v.w);
    out[i] = o;
  }
}

// ---------------- weights: transpose to [N][K] bf16 with COALESCED writes ----
// Each thread produces 8 consecutive k for one n: one 16B store. The strided
// w[k][c] reads hit L2 (weights are 2.25 MB each).
__global__ void prep_weights(const float* __restrict__ wq, const float* __restrict__ wk,
                             const float* __restrict__ wv, const float* __restrict__ wo,
                             const float* __restrict__ bq, const float* __restrict__ bk,
                             const float* __restrict__ bv,
                             unsigned short* __restrict__ wqkvT,
                             unsigned short* __restrict__ woT,
                             float* __restrict__ bqkv) {
  const int i0 = blockIdx.x * blockDim.x + threadIdx.x;
  const int stride = gridDim.x * blockDim.x;
  const int KB = EMB / 8;   // 96 eight-wide k-blocks per row
  for (int idx = i0; idx < NQKV * KB; idx += stride) {
    int n = idx / KB, k0 = (idx - n * KB) * 8;
    const float* w; int c;
    if (n < EMB)          { w = wq; c = n; }
    else if (n < 2 * EMB) { w = wk; c = n - EMB; }
    else                  { w = wv; c = n - 2 * EMB; }
    bf16x8 o;
#pragma unroll
    for (int i = 0; i < 8; ++i) o[i] = (short)f2bf(w[(size_t)(k0 + i) * EMB + c]);
    *(bf16x8*)(wqkvT + (size_t)n * EMB + k0) = o;
  }
  for (int idx = i0; idx < EMB * KB; idx += stride) {
    int n = idx / KB, k0 = (idx - n * KB) * 8;
    bf16x8 o;
#pragma unroll
    for (int i = 0; i < 8; ++i) o[i] = (short)f2bf(wo[(size_t)(k0 + i) * EMB + n]);
    *(bf16x8*)(woT + (size_t)n * EMB + k0) = o;
  }
  for (int idx = i0; idx < NQKV; idx += stride) {
    bqkv[idx] = (idx < EMB) ? bq[idx]
              : (idx < 2 * EMB ? bk[idx - EMB] : bv[idx - 2 * EMB]);
  }
}

// ---------------- 256x256 8-phase-style GEMM (round-5 version, known-good) ----
// MODE 0: C = bf16( (A*B + bias) * (col<768 ? 0.125 : 1) ), stride NQKV
// MODE 1: C = f32 ( A*B + bias ), stride EMB
template <int MODE>
__global__ __launch_bounds__(512, 2) void gemm256(const unsigned short* __restrict__ A,
                                                  const unsigned short* __restrict__ BT,
                                                  const float* __restrict__ bias,
                                                  void* __restrict__ Cout) {
  // slot s (s=0,1) at s*32768 shorts: A tile 256x64 at +0, B tile at +16384
  __shared__ unsigned short lds[2 * 32768];   // 128 KiB

  const int tid  = threadIdx.x;
  const int wave = tid >> 6;
  const int lane = tid & 63;
  const int wr = wave >> 2;        // 0..1  -> rows wr*128..+128
  const int wc = wave & 3;         // 0..3  -> cols wc*64..+64
  const int fr = lane & 15;
  const int fg = lane >> 4;        // 0..3

  // T1: bijective XCD swizzle (m204)
  const int ncol = gridDim.x;
  const int nwg  = gridDim.x * gridDim.y;
  const int orig = blockIdx.y * gridDim.x + blockIdx.x;
  const int q8   = nwg >> 3, r8 = nwg & 7;
  const int xcd  = orig & 7, off = orig >> 3;
  const int swz  = (xcd < r8 ? xcd * (q8 + 1) : r8 * (q8 + 1) + (xcd - r8) * q8) + off;
  const int brow = (swz / ncol) * 256;
  const int bcol = (swz % ncol) * 256;

  f32x4 acc[8][4] = {};

  const int grow = (wave >> 2) * 128 + (wave & 3) * 8 + (lane >> 3);
  const int srcc = (lane & 7) ^ ((lane >> 3) & 7);
  const unsigned short* gA = A  + (size_t)(brow + grow) * KDIM + srcc * 8;
  const unsigned short* gB = BT + (size_t)(bcol + grow) * KDIM + srcc * 8;
  const int wbase = (wave >> 2) * 8192 + (wave & 3) * 512;

  auto ALOAD = [&](int t, int j) {
    gload_lds16(gA + (size_t)(j * 32) * KDIM + t * 64,
                lds + (t & 1) * 32768 + wbase + j * 2048);
  };
  auto BLOAD = [&](int t, int j) {
    gload_lds16(gB + (size_t)(j * 32) * KDIM + t * 64,
                lds + (t & 1) * 32768 + 16384 + wbase + j * 2048);
  };

  const int rsw = fr & 7;          // read-side XOR on the 16B chunk index

  // prologue: stage tile 0 fully (B rounds then A rounds), wait all but A2,A3
  #pragma unroll
  for (int j = 0; j < 4; ++j) BLOAD(0, j);
  #pragma unroll
  for (int j = 0; j < 4; ++j) ALOAD(0, j);
  WAITV(2);
  __builtin_amdgcn_sched_barrier(0);
  __builtin_amdgcn_s_barrier();

  for (int t = 0; t < NKT; ++t) {
    const bool st = (t + 1 < NKT);             // stage tile t+1 this group
    const unsigned short* sb  = lds + (t & 1) * 32768;
    const unsigned short* sbB = sb + 16384;
    bf16x8 bfr[4][2];
    #pragma unroll
    for (int p = 0; p < 4; ++p) {
      // ---- ds_read: A quadrant (m = 2p, 2p+1), plus all B at p==0 ----
      if (p == 0) {
        #pragma unroll
        for (int n = 0; n < 4; ++n)
          #pragma unroll
          for (int kk = 0; kk < 2; ++kk)
            bfr[n][kk] = *(const bf16x8*)(sbB + (wc * 64 + n * 16 + fr) * 64 +
                                          (((kk * 4 + fg) ^ rsw) * 8));
      }
      bf16x8 afr[2][2];
      #pragma unroll
      for (int mi = 0; mi < 2; ++mi)
        #pragma unroll
        for (int kk = 0; kk < 2; ++kk)
          afr[mi][kk] = *(const bf16x8*)(sb + (wr * 128 + (2 * p + mi) * 16 + fr) * 64 +
                                         (((kk * 4 + fg) ^ rsw) * 8));
      // ---- stage 2 loads for tile t+1: p0:B01 p1:B23 p2:A01 p3:A23 ----
      if (st) {
        if (p < 2) { BLOAD(t + 1, 2 * p);     BLOAD(t + 1, 2 * p + 1); }
        else       { ALOAD(t + 1, 2 * p - 4); ALOAD(t + 1, 2 * p - 3); }
      }
      __builtin_amdgcn_sched_barrier(0);
      __builtin_amdgcn_s_barrier();
      asm volatile("s_waitcnt lgkmcnt(0)" ::: "memory");
      __builtin_amdgcn_sched_barrier(0);
      // ---- 16 MFMA ----
      __builtin_amdgcn_s_setprio(1);
      #pragma unroll
      for (int kk = 0; kk < 2; ++kk)
        #pragma unroll
        for (int mi = 0; mi < 2; ++mi)
          #pragma unroll
          for (int n = 0; n < 4; ++n)
            acc[2 * p + mi][n] = __builtin_amdgcn_mfma_f32_16x16x32_bf16(
                afr[mi][kk], bfr[n][kk], acc[2 * p + mi][n], 0, 0, 0);
      __builtin_amdgcn_s_setprio(0);
      __builtin_amdgcn_sched_barrier(0);
      // ---- counted vmcnt (T4): never drain to 0 while staging ----
      if (p == 1) { if (st) { WAITV(4); } else { WAITV(0); } }
      if (p == 3 && st) { WAITV(2); }
      __builtin_amdgcn_s_barrier();
    }
  }

  // epilogue: n innermost so both 32B halves of each 64B line store back-to-back
  float bvals[4];
#pragma unroll
  for (int n = 0; n < 4; ++n) bvals[n] = bias[bcol + wc * 64 + n * 16 + fr];
#pragma unroll
  for (int m = 0; m < 8; ++m) {
#pragma unroll
    for (int r = 0; r < 4; ++r) {
      const int row = brow + wr * 128 + m * 16 + fg * 4 + r;
#pragma unroll
      for (int n = 0; n < 4; ++n) {
        const int col = bcol + wc * 64 + n * 16 + fr;
        float v = acc[m][n][r] + bvals[n];
        if (MODE == 0) {
          if (col < EMB) v *= 0.125f;
          ((unsigned short*)Cout)[(size_t)row * NQKV + col] = f2bf(v);
        } else {
          ((float*)Cout)[(size_t)row * EMB + col] = v;
        }
      }
    }
  }
}

// ---------------- attention: one block per (b,h), 5 waves (16-row stripes) ----
// Q AND K fragments load directly from global (L2-hot, 16B-contiguous) -> no
// k_lds, no pre-QK^T barrier. Only V is transposed through LDS; ONE
// __syncthreads before PV. LDS 30 KB -> 5 blocks/CU. K pad rows (77..79) read
// garbage that the causal mask kills (reads stay inside d_ws).
#define SV 104
__global__ __launch_bounds__(320) void attn_kernel(const unsigned short* __restrict__ qkv,
                                                   unsigned short* __restrict__ attn_out) {
  __shared__ unsigned short vT_lds[64 * SV];   // [d][t], stride 104
  __shared__ unsigned short p_lds[80 * SV];    // [s][t], stride 104

  const int tid  = threadIdx.x;
  const int wv_  = tid >> 6;   // stripe 0..4
  const int lane = tid & 63;
  const int fr = lane & 15;
  const int fg = lane >> 4;

  const int bh = blockIdx.x;
  const int b  = bh / NHEAD;
  const int h  = bh - b * NHEAD;

  const size_t base = (size_t)b * S_LEN * NQKV + (size_t)h * DHEAD;

  // Q fragments (this stripe's rows) + K fragments (all t rows) direct to regs
  bf16x8 qfr[2], kfr[5][2];
  {
    const int srow = wv_ * 16 + fr;
    const int qs = (srow < S_LEN) ? srow : 0;   // clamp: pad rows discarded later
    const unsigned short* qg = qkv + base + (size_t)qs * NQKV + fg * 8;
    qfr[0] = *(const bf16x8*)(qg);
    qfr[1] = *(const bf16x8*)(qg + 32);
    const unsigned short* kg = qkv + base + EMB + fg * 8;
#pragma unroll
    for (int n = 0; n < 5; ++n)
#pragma unroll
      for (int kk = 0; kk < 2; ++kk)
        kfr[n][kk] = *(const bf16x8*)(kg + (size_t)(n * 16 + fr) * NQKV + kk * 32);
  }

  // zero ONLY the pad strips PV multiplies by nonzero values:
  //   vT cols 77..95 (64 rows x 19), p cols 80..95 (80 rows x 16)
  for (int i = tid; i < 64 * 19; i += 320) {
    int d = i / 19, c = 77 + (i - d * 19);
    vT_lds[d * SV + c] = 0;
  }
  for (int i = tid; i < 80 * 16; i += 320) {
    int s = i >> 4, c = 80 + (i & 15);
    p_lds[s * SV + c] = 0;
  }

  // stage transposed V (strips above are disjoint from these writes)
  for (int idx = tid; idx < S_LEN * 32; idx += 320) {
    int s = idx >> 5, c = idx & 31;
    unsigned int vx = *(const unsigned int*)(qkv + base + (size_t)s * NQKV + 2 * EMB + c * 2);
    vT_lds[(c * 2 + 0) * SV + s] = (unsigned short)(vx & 0xffffu);
    vT_lds[(c * 2 + 1) * SV + s] = (unsigned short)(vx >> 16);
  }

  // QK^T : scores[s][t] from registers only — no barrier needed
  f32x4 sc[5];
#pragma unroll
  for (int n = 0; n < 5; ++n) sc[n] = (f32x4){0.f, 0.f, 0.f, 0.f};
#pragma unroll
  for (int kk = 0; kk < 2; ++kk)
#pragma unroll
    for (int n = 0; n < 5; ++n)
      sc[n] = __builtin_amdgcn_mfma_f32_16x16x32_bf16(qfr[kk], kfr[n][kk], sc[n], 0, 0, 0);

  // causal softmax; rows per lane: s = wv_*16 + fg*4 + r, cols t = n*16 + fr
  float mrow[4], ssum[4];
#pragma unroll
  for (int r = 0; r < 4; ++r) {
    const int s_loc = wv_ * 16 + fg * 4 + r;
    float mx = -1e30f;
#pragma unroll
    for (int n = 0; n < 5; ++n) {
      const int t = n * 16 + fr;
      float val = ((t <= s_loc) && (t < S_LEN)) ? sc[n][r] : -1e30f;
      sc[n][r] = val;
      mx = fmaxf(mx, val);
    }
    mrow[r] = mx;
  }
#pragma unroll
  for (int off = 1; off < 16; off <<= 1)
#pragma unroll
    for (int r = 0; r < 4; ++r)
      mrow[r] = fmaxf(mrow[r], __shfl_xor(mrow[r], off, 64));
#pragma unroll
  for (int r = 0; r < 4; ++r) {
    float sm = 0.f;
#pragma unroll
    for (int n = 0; n < 5; ++n) {
      float p = __expf(sc[n][r] - mrow[r]);
      sc[n][r] = p;
      sm += p;
    }
    ssum[r] = sm;
  }
#pragma unroll
  for (int off = 1; off < 16; off <<= 1)
#pragma unroll
    for (int r = 0; r < 4; ++r)
      ssum[r] += __shfl_xor(ssum[r], off, 64);

#pragma unroll
  for (int r = 0; r < 4; ++r) {
    const int srow = wv_ * 16 + fg * 4 + r;
    const float inv = 1.0f / ssum[r];
#pragma unroll
    for (int n = 0; n < 5; ++n)
      p_lds[srow * SV + n * 16 + fr] = f2bf(sc[n][r] * inv);
  }
  // ONE barrier: vT (cross-wave) + p (wave-local) both complete before PV
  __syncthreads();

  // PV : out[s][d] = sum_t p[s][t] * v[t][d], t padded to 96 (pad strips zero)
  f32x4 o[4];
#pragma unroll
  for (int n = 0; n < 4; ++n) o[n] = (f32x4){0.f, 0.f, 0.f, 0.f};
#pragma unroll
  for (int kk = 0; kk < 96; kk += 32) {
    bf16x8 afr = *(const bf16x8*)(p_lds + (wv_ * 16 + fr) * SV + kk + fg * 8);
#pragma unroll
    for (int n = 0; n < 4; ++n) {
      bf16x8 bfr = *(const bf16x8*)(vT_lds + (n * 16 + fr) * SV + kk + fg * 8);
      o[n] = __builtin_amdgcn_mfma_f32_16x16x32_bf16(afr, bfr, o[n], 0, 0, 0);
    }
  }

  const size_t obase = (size_t)b * S_LEN * EMB + (size_t)h * DHEAD;
#pragma unroll
  for (int r = 0; r < 4; ++r) {
    const int srow = wv_ * 16 + fg * 4 + r;
    if (srow < S_LEN) {
#pragma unroll
      for (int n = 0; n < 4; ++n)
        attn_out[obase + (size_t)srow * EMB + n * 16 + fr] = f2bf(o[n][r]);
    }
  }
}

extern "C" void kernel_launch(void* const* d_in, const int* in_sizes, int n_in,
                              void* d_out, int out_size, void* d_ws, size_t ws_size,
                              hipStream_t stream) {
  const float* x  = (const float*)d_in[0];
  const float* wq = (const float*)d_in[1];
  const float* bq = (const float*)d_in[2];
  const float* wk = (const float*)d_in[3];
  const float* bk = (const float*)d_in[4];
  const float* wv = (const float*)d_in[5];
  const float* bv = (const float*)d_in[6];
  const float* wo = (const float*)d_in[7];
  const float* bo = (const float*)d_in[8];
  (void)in_sizes; (void)n_in; (void)out_size; (void)ws_size;

  char* ws = (char*)d_ws;
  // layout (bytes):
  unsigned short* x_bf   = (unsigned short*)(ws);                  // M*E bf16      = 60,555,264
  unsigned short* wqkvT  = (unsigned short*)(ws + 60555264ULL);    // 2304*768 bf16 =  3,538,944
  unsigned short* woT    = (unsigned short*)(ws + 64094208ULL);    // 768*768 bf16  =  1,179,648
  float*          bqkv   = (float*)         (ws + 65273856ULL);    // 2304 f32      =      9,216
  unsigned short* qkv    = (unsigned short*)(ws + 65283072ULL);    // M*2304 bf16   = 181,665,792
  unsigned short* attn_o = (unsigned short*)(ws + 246948864ULL);   // M*768 bf16    = 60,555,264

  cvt_f32_bf16<<<2048, 256, 0, stream>>>((const float4*)x, (ushort4*)x_bf, MROWS * EMB / 4);
  prep_weights<<<1024, 256, 0, stream>>>(wq, wk, wv, wo, bq, bk, bv, wqkvT, woT, bqkv);
  gemm256<0><<<dim3(NQKV / 256, MROWS / 256), 512, 0, stream>>>(x_bf, wqkvT, bqkv, qkv);
  attn_kernel<<<BATCH * NHEAD, 320, 0, stream>>>(qkv, attn_o);
  gemm256<1><<<dim3(EMB / 256, MROWS / 256), 512, 0, stream>>>(attn_o, woT, bo, d_out);
}